// Round 10
// baseline (62.061 us; speedup 1.0000x reference)
//
#include <hip/hip_runtime.h>
#include <stdint.h>

typedef _Float16 f16x8 __attribute__((ext_vector_type(8)));
typedef __fp16 fp16x2 __attribute__((ext_vector_type(2)));
typedef float f32x4 __attribute__((ext_vector_type(4)));

#define BC (16384 * 256)

__device__ __forceinline__ f16x8 cvt8(f32x4 a, f32x4 b) {
  fp16x2 p0 = __builtin_amdgcn_cvt_pkrtz(a[0], a[1]);
  fp16x2 p1 = __builtin_amdgcn_cvt_pkrtz(a[2], a[3]);
  fp16x2 p2 = __builtin_amdgcn_cvt_pkrtz(b[0], b[1]);
  fp16x2 p3 = __builtin_amdgcn_cvt_pkrtz(b[2], b[3]);
  f16x8 o;
  o[0] = (_Float16)p0[0]; o[1] = (_Float16)p0[1];
  o[2] = (_Float16)p1[0]; o[3] = (_Float16)p1[1];
  o[4] = (_Float16)p2[0]; o[5] = (_Float16)p2[1];
  o[6] = (_Float16)p3[0]; o[7] = (_Float16)p3[1];
  return o;
}

__device__ __forceinline__ float tanh_fast(float v) {
  float a = fminf(fabsf(v), 18.f);
  float t = __expf(2.f * a);
  float r = (t - 1.f) * __builtin_amdgcn_rcpf(t + 1.f);
  return copysignf(r, v);
}

// Pack Wu/Wg/Wa/Wd -> wsB f16, PRE-SWIZZLED (R6 layout, verified):
// wsB[cb*65536 + row*512 + kt*64 + slot*8 + b] where
//   row = wn*64 + strip*16 + t16, c = cb*32 + wn*16 + t16,
//   k = kt*64 + (slot ^ (row&7))*8 + b  (XOR swizzle baked in).
// strip: 0=Wu (K zero-padded for k>=256), 1=Wg, 2=Wa, 3=Wd.
__global__ __launch_bounds__(256) void pack_w(const float* __restrict__ Wu,
                                              const float* __restrict__ Wg,
                                              const float* __restrict__ Wa,
                                              const float* __restrict__ Wd,
                                              _Float16* __restrict__ wsB) {
  int t = blockIdx.x * 256 + threadIdx.x;  // 65536 total
  int slot = t & 7;
  int kt = (t >> 3) & 7;
  int row = (t >> 6) & 127;
  int cb = t >> 13;
  int strip = (row >> 4) & 3;
  int wn = row >> 6;
  int t16 = row & 15;
  int c = cb * 32 + wn * 16 + t16;
  int k0 = kt * 64 + (slot ^ (row & 7)) * 8;
  float v[8];
  if (strip == 0) {
    if (k0 < 256) {
      const float* p = Wu + (size_t)c * 256 + k0;
#pragma unroll
      for (int i = 0; i < 8; ++i) v[i] = p[i];
    } else {
#pragma unroll
      for (int i = 0; i < 8; ++i) v[i] = 0.f;
    }
  } else {
    const float* p = (strip == 1 ? Wg : (strip == 2 ? Wa : Wd)) + (size_t)c * 512 + k0;
#pragma unroll
    for (int i = 0; i < 8; ++i) v[i] = p[i];
  }
  f32x4 a = {v[0], v[1], v[2], v[3]};
  f32x4 b = {v[4], v[5], v[6], v[7]};
  *reinterpret_cast<f16x8*>(wsB + (size_t)cb * 65536 + row * 512 + kt * 64 + slot * 8) =
      cvt8(a, b);
}

// Occupancy-max fused GEMM + epilogue.
// Block: 128 rows x 128 packed cols, 8 waves (4M x 2N), BK=64, 32 KB LDS
// single-buffered, 2 barriers/kt. VGPR <= 64 (launch_bounds 512,8) ->
// 4 blocks/CU x 8 waves = 32 waves/CU; grid 1024 = exactly one round.
__global__ __launch_bounds__(512, 8) void rwa_main(
    const float* __restrict__ x, const float* __restrict__ nt_,
    const float* __restrict__ dt_, const float* __restrict__ h,
    const float* __restrict__ amax_, const float* __restrict__ bu,
    const float* __restrict__ bg, const _Float16* __restrict__ wsB,
    float* __restrict__ out) {
  __shared__ __align__(16) _Float16 ldsA[128 * 64];  // 16 KB
  __shared__ __align__(16) _Float16 ldsB[128 * 64];  // 16 KB

  const int tid = threadIdx.x;
  const int lane = tid & 63;
  const int l15 = lane & 15;
  const int lg = lane >> 4;
  const int wv = tid >> 6;   // 0..7
  const int wm = wv & 3;     // wave row-quarter (32 rows)
  const int wn = wv >> 2;    // wave packed-col half (64)

  // XCD swizzle: per XCD, cb fastest -> row panels + weights L2-hot.
  const int bid = blockIdx.x;  // 0..1023
  const int xcd = bid & 7;
  const int q = bid >> 3;      // 0..127
  const int cb = q & 7;
  const int rowblk = xcd * 16 + (q >> 3);  // 0..127
  const int row0 = rowblk * 128;

  // A staging: thread stages row ar (0..127), k-quarter aq (16 floats).
  const int ar = tid >> 2;
  const int aq = tid & 3;

  // B staging source (R6 layout): row = tid>>3 (+64 per round), slot = tid&7.
  const _Float16* bsrc0 = wsB + (size_t)cb * 65536 + (tid >> 3) * 512 + (tid & 7) * 8;

  f32x4 acc[2][4] = {};  // [mi][strip]

  for (int kt = 0; kt < 8; ++kt) {
    // --- stage B: 2x global_load_lds dwordx4 (linear dest, pre-swizzled src) ---
#pragma unroll
    for (int i = 0; i < 2; ++i) {
      __builtin_amdgcn_global_load_lds(
          (const __attribute__((address_space(1))) uint32_t*)(bsrc0 + (size_t)kt * 64 + i * 32768),
          (__attribute__((address_space(3))) uint32_t*)(ldsB + wv * 512 + i * 4096),
          16, 0, 0);
    }
    // --- stage A: coalesced f32 loads, cvt f16, swizzled ds_write ---
    {
      const float* asrc =
          (kt < 4 ? x : h) + (size_t)(row0 + ar) * 256 + (kt & 3) * 64 + aq * 16;
      f32x4 av[4];
#pragma unroll
      for (int i = 0; i < 4; ++i) av[i] = *reinterpret_cast<const f32x4*>(asrc + i * 4);
#pragma unroll
      for (int j = 0; j < 2; ++j) {
        f16x8 o = cvt8(av[2 * j], av[2 * j + 1]);
        const int slot = (aq * 2 + j) ^ (ar & 7);
        *reinterpret_cast<f16x8*>(reinterpret_cast<char*>(ldsA) + ar * 128 + slot * 16) = o;
      }
    }
    __syncthreads();

    // --- compute ---
    const bool doU = (kt < 4);  // Wu strip zero-padded beyond k=256
    const int rswz = (l15 & 7) << 4;
#pragma unroll
    for (int ks = 0; ks < 2; ++ks) {
      f16x8 af[2], bf[4];
#pragma unroll
      for (int mi = 0; mi < 2; ++mi) {
        const int row = wm * 32 + mi * 16 + l15;
        af[mi] = *reinterpret_cast<const f16x8*>(
            reinterpret_cast<const char*>(ldsA) + row * 128 + ((ks * 64 + lg * 16) ^ rswz));
      }
#pragma unroll
      for (int s = 0; s < 4; ++s) {
        if (s == 0 && !doU) continue;
        const int pc = wn * 64 + s * 16 + l15;
        bf[s] = *reinterpret_cast<const f16x8*>(
            reinterpret_cast<const char*>(ldsB) + pc * 128 + ((ks * 64 + lg * 16) ^ rswz));
      }
#pragma unroll
      for (int s = 0; s < 4; ++s) {
        if (s == 0 && !doU) continue;
#pragma unroll
        for (int mi = 0; mi < 2; ++mi)
          acc[mi][s] = __builtin_amdgcn_mfma_f32_16x16x32_f16(af[mi], bf[s], acc[mi][s], 0, 0, 0);
      }
    }
    __syncthreads();
  }

  // --- epilogue: lane owns (r,c); u,g,a,dec local ---
  const int c = cb * 32 + wn * 16 + l15;
  const float buv = bu[c];
  const float bgv = bg[c];
#pragma unroll
  for (int mi = 0; mi < 2; ++mi) {
#pragma unroll
    for (int rg = 0; rg < 4; ++rg) {
      const int r = row0 + wm * 32 + mi * 16 + lg * 4 + rg;
      const int idx = r * 256 + c;
      const float u = acc[mi][0][rg] + buv;
      const float gt = acc[mi][1][rg] + bgv;
      const float a = acc[mi][2][rg];
      const float dr = acc[mi][3][rg];
      const float sig = __builtin_amdgcn_rcpf(1.f + __expf(-dr));
      const float z = u * tanh_fast(gt);
      const float am = amax_[idx];
      const float n_old = nt_[idx];
      const float d_old = dt_[idx];
      const float e_neg = __expf(-sig);
      const float a_new = fmaxf(am * e_neg, a);
      const float comm = __expf(am - a_new - sig);  // e_neg * exp(am - a_new)
      const float escal = __expf(a - a_new);
      const float n_new = n_old * comm + z * escal;
      const float d_new = d_old * comm + escal;
      const float h_new = tanh_fast(n_new * __builtin_amdgcn_rcpf(d_new));
      out[idx] = n_new;
      out[BC + idx] = d_new;
      out[2 * BC + idx] = h_new;
      out[3 * BC + idx] = a_new;
    }
  }
}

extern "C" void kernel_launch(void* const* d_in, const int* in_sizes, int n_in,
                              void* d_out, int out_size, void* d_ws, size_t ws_size,
                              hipStream_t stream) {
  const float* x_t    = (const float*)d_in[0];
  const float* n_t    = (const float*)d_in[1];
  const float* d_t    = (const float*)d_in[2];
  const float* h_t    = (const float*)d_in[3];
  const float* amax_t = (const float*)d_in[4];
  const float* Wu     = (const float*)d_in[5];
  const float* bu     = (const float*)d_in[6];
  const float* Wg     = (const float*)d_in[7];
  const float* bg     = (const float*)d_in[8];
  const float* Wa     = (const float*)d_in[9];
  const float* Wd     = (const float*)d_in[10];
  float* out = (float*)d_out;

  _Float16* wsB = (_Float16*)d_ws;  // 1 MB pre-swizzled packed weights

  pack_w<<<256, 256, 0, stream>>>(Wu, Wg, Wa, Wd, wsB);
  rwa_main<<<1024, 512, 0, stream>>>(x_t, n_t, d_t, h_t, amax_t, bu, bg, wsB, out);
}